// Round 9
// baseline (559.258 us; speedup 1.0000x reference)
//
#include <hip/hip_runtime.h>
#include <hip/hip_fp16.h>
#include <hip/hip_cooperative_groups.h>

namespace cg = cooperative_groups;

// Masked Sinkhorn via diagonal-scaling algebra on A = s+EPS:
//   c <- 1/(A^T r), r <- 1/(A c), out = A ∘ (r9 c8^T) on valid block.
// R9 = R8 with the compile fix (hipDeviceAttributeMultiprocessorCount — note
// lowercase 'p'). One cooperative dispatch, grid.sync() between the 6 phases;
// bodies identical to R7's proven 230us kernels (absmax must stay 3.0518e-05).
// Fallback to R7's 6-dispatch path if coop occupancy is insufficient.

namespace {
constexpr int B_ = 64;
constexpr int N_ = 1024;
constexpr int M_ = 1024;
constexpr float EPS_ = 1e-4f;
constexpr int PCHUNK = 16;        // row chunks for column-sum partials
constexpr int RPC = N_ / PCHUNK;  // 64 rows per chunk
constexpr int NVB = PCHUNK * B_;  // 1024 virtual blocks per phase
}

typedef float f32x4_ __attribute__((ext_vector_type(4)));

__device__ __forceinline__ float4 nt_load4(const float* p) {
    f32x4_ v = __builtin_nontemporal_load(reinterpret_cast<const f32x4_*>(p));
    return float4{v.x, v.y, v.z, v.w};
}

// ---------------------------------------------------------------------------
// Phase bodies (identical math to R7's kernels).
// ---------------------------------------------------------------------------

// Prep: q = fp16(s+EPS) for valid rows (zeros beyond nc), + iter-0 col partials.
__device__ __forceinline__ void prep_body(int b, int p,
                                          const float* __restrict__ s,
                                          __half* __restrict__ q,
                                          float* __restrict__ partial,
                                          const int* __restrict__ nrows,
                                          const int* __restrict__ ncols,
                                          float (*lds)[M_]) {
    const int nr = nrows[b], nc = ncols[b];
    const int wave = threadIdx.x >> 6, lane = threadIdx.x & 63;

    float4 ca[4];
#pragma unroll
    for (int t = 0; t < 4; ++t) ca[t] = float4{0.f, 0.f, 0.f, 0.f};

    const int rbeg = p * RPC + wave * 16;
    const int rend = min(rbeg + 16, nr);
    const float* sb = s + (size_t)b * N_ * M_;
    __half* qb = q + (size_t)b * N_ * M_;

    for (int n = rbeg; n < rend; ++n) {
#pragma unroll
        for (int t = 0; t < 4; ++t) {
            const int m0 = t * 256 + lane * 4;
            float4 v = {0.f, 0.f, 0.f, 0.f};
            if (m0 < nc) {
                v = nt_load4(sb + (size_t)n * M_ + m0);
                v.x += EPS_; v.y += EPS_; v.z += EPS_; v.w += EPS_;
            }
            __half2 h01 = __floats2half2_rn(v.x, v.y);
            __half2 h23 = __floats2half2_rn(v.z, v.w);
            uint2 st;
            st.x = *reinterpret_cast<const unsigned*>(&h01);
            st.y = *reinterpret_cast<const unsigned*>(&h23);
            *reinterpret_cast<uint2*>(qb + (size_t)n * M_ + m0) = st;
            ca[t].x += v.x; ca[t].y += v.y; ca[t].z += v.z; ca[t].w += v.w;
        }
    }
    __syncthreads();  // LDS reuse safety (phase/vb boundaries)
#pragma unroll
    for (int t = 0; t < 4; ++t)
        *reinterpret_cast<float4*>(&lds[wave][t * 256 + lane * 4]) = ca[t];
    __syncthreads();
    const int m0 = threadIdx.x * 4;
    const float4 a0 = *reinterpret_cast<const float4*>(&lds[0][m0]);
    const float4 a1 = *reinterpret_cast<const float4*>(&lds[1][m0]);
    const float4 a2 = *reinterpret_cast<const float4*>(&lds[2][m0]);
    const float4 a3 = *reinterpret_cast<const float4*>(&lds[3][m0]);
    float4 o;
    o.x = a0.x + a1.x + a2.x + a3.x;
    o.y = a0.y + a1.y + a2.y + a3.y;
    o.z = a0.z + a1.z + a2.z + a3.z;
    o.w = a0.w + a1.w + a2.w + a3.w;
    *reinterpret_cast<float4*>(partial + ((size_t)b * PCHUNK + p) * M_ + m0) = o;
}

// Fused pair: c = 1/reduce(partial_in); r = 1/(q c) per row; col partials of
// q^T r -> partial_out.
__device__ __forceinline__ void fused_body(int b, int p,
                                           const __half* __restrict__ q,
                                           const float* __restrict__ partial_in,
                                           float* __restrict__ partial_out,
                                           const int* __restrict__ nrows,
                                           const int* __restrict__ ncols,
                                           float (*lds)[M_]) {
    const int nr = nrows[b], nc = ncols[b];
    const int wave = threadIdx.x >> 6, lane = threadIdx.x & 63;

    __syncthreads();  // LDS reuse safety
    // phase 1: c = 1/colsum into lds[0][.]
    {
        const int m0 = threadIdx.x * 4;
        const float* pp = partial_in + (size_t)b * PCHUNK * M_ + m0;
        float4 sacc = {0.f, 0.f, 0.f, 0.f};
#pragma unroll
        for (int i = 0; i < PCHUNK; ++i) {
            const float4 v = *reinterpret_cast<const float4*>(pp + (size_t)i * M_);
            sacc.x += v.x; sacc.y += v.y; sacc.z += v.z; sacc.w += v.w;
        }
        float4 cv;
        cv.x = (sacc.x == 0.f) ? 1.f : 1.f / sacc.x;
        cv.y = (sacc.y == 0.f) ? 1.f : 1.f / sacc.y;
        cv.z = (sacc.z == 0.f) ? 1.f : 1.f / sacc.z;
        cv.w = (sacc.w == 0.f) ? 1.f : 1.f / sacc.w;
        *reinterpret_cast<float4*>(&lds[0][m0]) = cv;
    }
    __syncthreads();

    // phase 2: lane's 16 c values, masked to 0 beyond nc
    float cm[16];
#pragma unroll
    for (int t = 0; t < 2; ++t)
#pragma unroll
        for (int j = 0; j < 8; ++j) {
            const int m = t * 512 + lane * 8 + j;
            const float v = lds[0][m];
            cm[t * 8 + j] = (m < nc) ? v : 0.f;
        }
    __syncthreads();  // lds reused for the column-partial combine below

    // phase 3: rows — dot -> r_n, accumulate q*r_n into column accumulators
    float ca[16];
#pragma unroll
    for (int k = 0; k < 16; ++k) ca[k] = 0.f;

    const int rbeg = p * RPC + wave * 16;
    const int rend = min(rbeg + 16, nr);
    const __half* qb = q + (size_t)b * N_ * M_;

    for (int n = rbeg; n < rend; ++n) {
        float f[16];
#pragma unroll
        for (int t = 0; t < 2; ++t) {
            const float4 raw = *reinterpret_cast<const float4*>(
                qb + (size_t)n * M_ + t * 512 + lane * 8);
            const __half2* hp = reinterpret_cast<const __half2*>(&raw);
#pragma unroll
            for (int k = 0; k < 4; ++k) {
                const float2 fr = __half22float2(hp[k]);
                f[t * 8 + 2 * k] = fr.x;
                f[t * 8 + 2 * k + 1] = fr.y;
            }
        }
        float acc = 0.f;
#pragma unroll
        for (int k = 0; k < 16; ++k) acc = fmaf(f[k], cm[k], acc);
#pragma unroll
        for (int off = 1; off < 64; off <<= 1)
            acc += __shfl_xor(acc, off, 64);
        const float rn = 1.f / acc;  // acc > 0 always (q,c > 0 on valid cols)
#pragma unroll
        for (int k = 0; k < 16; ++k) ca[k] = fmaf(f[k], rn, ca[k]);
    }

    // phase 4: combine 4 waves -> partial_out[b][p][:]
#pragma unroll
    for (int t = 0; t < 2; ++t) {
        float4 v0 = {ca[t * 8 + 0], ca[t * 8 + 1], ca[t * 8 + 2], ca[t * 8 + 3]};
        float4 v1 = {ca[t * 8 + 4], ca[t * 8 + 5], ca[t * 8 + 6], ca[t * 8 + 7]};
        *reinterpret_cast<float4*>(&lds[wave][t * 512 + lane * 8]) = v0;
        *reinterpret_cast<float4*>(&lds[wave][t * 512 + lane * 8 + 4]) = v1;
    }
    __syncthreads();
    const int m0 = threadIdx.x * 4;
    const float4 a0 = *reinterpret_cast<const float4*>(&lds[0][m0]);
    const float4 a1 = *reinterpret_cast<const float4*>(&lds[1][m0]);
    const float4 a2 = *reinterpret_cast<const float4*>(&lds[2][m0]);
    const float4 a3 = *reinterpret_cast<const float4*>(&lds[3][m0]);
    float4 o;
    o.x = a0.x + a1.x + a2.x + a3.x;
    o.y = a0.y + a1.y + a2.y + a3.y;
    o.z = a0.z + a1.z + a2.z + a3.z;
    o.w = a0.w + a1.w + a2.w + a3.w;
    *reinterpret_cast<float4*>(partial_out + ((size_t)b * PCHUNK + p) * M_ + m0) = o;
}

// Final: c8 = 1/reduce(partial_in); r9 = 1/(q c8); out = q*r9*c8 (regular
// float4 stores — NT stores caused 2.17x write amplification, R6 counters).
__device__ __forceinline__ void final_body(int b, int p,
                                           const __half* __restrict__ q,
                                           const float* __restrict__ partial_in,
                                           float* __restrict__ out,
                                           const int* __restrict__ nrows,
                                           const int* __restrict__ ncols,
                                           float* ldsc) {
    const int nr = nrows[b], nc = ncols[b];
    const int wave = threadIdx.x >> 6, lane = threadIdx.x & 63;

    __syncthreads();  // LDS reuse safety
    {
        const int m0 = threadIdx.x * 4;
        const float* pp = partial_in + (size_t)b * PCHUNK * M_ + m0;
        float4 sacc = {0.f, 0.f, 0.f, 0.f};
#pragma unroll
        for (int i = 0; i < PCHUNK; ++i) {
            const float4 v = *reinterpret_cast<const float4*>(pp + (size_t)i * M_);
            sacc.x += v.x; sacc.y += v.y; sacc.z += v.z; sacc.w += v.w;
        }
        float4 cv;
        cv.x = (sacc.x == 0.f) ? 1.f : 1.f / sacc.x;
        cv.y = (sacc.y == 0.f) ? 1.f : 1.f / sacc.y;
        cv.z = (sacc.z == 0.f) ? 1.f : 1.f / sacc.z;
        cv.w = (sacc.w == 0.f) ? 1.f : 1.f / sacc.w;
        *reinterpret_cast<float4*>(&ldsc[m0]) = cv;
    }
    __syncthreads();

    float cm[16];
#pragma unroll
    for (int t = 0; t < 2; ++t)
#pragma unroll
        for (int j = 0; j < 8; ++j) {
            const int m = t * 512 + lane * 8 + j;
            const float v = ldsc[m];
            cm[t * 8 + j] = (m < nc) ? v : 0.f;
        }

    const int rbeg = p * RPC + wave * 16;
    const __half* qb = q + (size_t)b * N_ * M_;
    float* ob = out + (size_t)b * N_ * M_;

    for (int n = rbeg; n < rbeg + 16; ++n) {
        if (n >= nr) {  // zero row (wave-uniform branch)
            const float4 z = {0.f, 0.f, 0.f, 0.f};
#pragma unroll
            for (int t = 0; t < 2; ++t) {
                *reinterpret_cast<float4*>(ob + (size_t)n * M_ + t * 512 + lane * 8) = z;
                *reinterpret_cast<float4*>(ob + (size_t)n * M_ + t * 512 + lane * 8 + 4) = z;
            }
            continue;
        }
        float f[16];
#pragma unroll
        for (int t = 0; t < 2; ++t) {
            const float4 raw = *reinterpret_cast<const float4*>(
                qb + (size_t)n * M_ + t * 512 + lane * 8);
            const __half2* hp = reinterpret_cast<const __half2*>(&raw);
#pragma unroll
            for (int k = 0; k < 4; ++k) {
                const float2 fr = __half22float2(hp[k]);
                f[t * 8 + 2 * k] = fr.x;
                f[t * 8 + 2 * k + 1] = fr.y;
            }
        }
        float acc = 0.f;
#pragma unroll
        for (int k = 0; k < 16; ++k) acc = fmaf(f[k], cm[k], acc);
#pragma unroll
        for (int off = 1; off < 64; off <<= 1)
            acc += __shfl_xor(acc, off, 64);
        const float rn = 1.f / acc;
#pragma unroll
        for (int t = 0; t < 2; ++t) {
            float4 o0, o1;
            o0.x = f[t * 8 + 0] * rn * cm[t * 8 + 0];
            o0.y = f[t * 8 + 1] * rn * cm[t * 8 + 1];
            o0.z = f[t * 8 + 2] * rn * cm[t * 8 + 2];
            o0.w = f[t * 8 + 3] * rn * cm[t * 8 + 3];
            o1.x = f[t * 8 + 4] * rn * cm[t * 8 + 4];
            o1.y = f[t * 8 + 5] * rn * cm[t * 8 + 5];
            o1.z = f[t * 8 + 6] * rn * cm[t * 8 + 6];
            o1.w = f[t * 8 + 7] * rn * cm[t * 8 + 7];
            *reinterpret_cast<float4*>(ob + (size_t)n * M_ + t * 512 + lane * 8) = o0;
            *reinterpret_cast<float4*>(ob + (size_t)n * M_ + t * 512 + lane * 8 + 4) = o1;
        }
    }
}

// ---------------------------------------------------------------------------
// Cooperative single-dispatch kernel: all 6 phases, grid.sync between them.
// Grid-stride over 1024 virtual blocks -> correct for any co-resident grid.
__global__ void __launch_bounds__(256, 4)
sink_coop(const float* __restrict__ s, __half* __restrict__ q,
          float* __restrict__ pa, float* __restrict__ pb,
          float* __restrict__ out, const int* __restrict__ nrows,
          const int* __restrict__ ncols) {
    __shared__ float lds[4][M_];
    cg::grid_group grid = cg::this_grid();

    for (int vb = blockIdx.x; vb < NVB; vb += gridDim.x)
        prep_body(vb >> 4, vb & 15, s, q, pa, nrows, ncols, lds);
    grid.sync();
    for (int vb = blockIdx.x; vb < NVB; vb += gridDim.x)
        fused_body(vb >> 4, vb & 15, q, pa, pb, nrows, ncols, lds);  // c0->r1->p(c2)
    grid.sync();
    for (int vb = blockIdx.x; vb < NVB; vb += gridDim.x)
        fused_body(vb >> 4, vb & 15, q, pb, pa, nrows, ncols, lds);  // c2->r3->p(c4)
    grid.sync();
    for (int vb = blockIdx.x; vb < NVB; vb += gridDim.x)
        fused_body(vb >> 4, vb & 15, q, pa, pb, nrows, ncols, lds);  // c4->r5->p(c6)
    grid.sync();
    for (int vb = blockIdx.x; vb < NVB; vb += gridDim.x)
        fused_body(vb >> 4, vb & 15, q, pb, pa, nrows, ncols, lds);  // c6->r7->p(c8)
    grid.sync();
    for (int vb = blockIdx.x; vb < NVB; vb += gridDim.x)
        final_body(vb >> 4, vb & 15, q, pa, out, nrows, ncols, lds[0]);  // c8->r9->out
}

// ---------------------------------------------------------------------------
// Fallback: R7's proven 6-dispatch path (same bodies).
__global__ void prep_pass(const float* __restrict__ s, __half* __restrict__ q,
                          float* __restrict__ partial,
                          const int* __restrict__ nrows, const int* __restrict__ ncols) {
    __shared__ float lds[4][M_];
    prep_body(blockIdx.y, blockIdx.x, s, q, partial, nrows, ncols, lds);
}
__global__ void fused_pass_h(const __half* __restrict__ q,
                             const float* __restrict__ partial_in,
                             float* __restrict__ partial_out,
                             const int* __restrict__ nrows, const int* __restrict__ ncols) {
    __shared__ float lds[4][M_];
    fused_body(blockIdx.y, blockIdx.x, q, partial_in, partial_out, nrows, ncols, lds);
}
__global__ void final_pass_h(const __half* __restrict__ q,
                             const float* __restrict__ partial_in,
                             float* __restrict__ out,
                             const int* __restrict__ nrows, const int* __restrict__ ncols) {
    __shared__ float ldsc[M_];
    final_body(blockIdx.y, blockIdx.x, q, partial_in, out, nrows, ncols, ldsc);
}

// ---------------------------------------------------------------------------
extern "C" void kernel_launch(void* const* d_in, const int* in_sizes, int n_in,
                              void* d_out, int out_size, void* d_ws, size_t ws_size,
                              hipStream_t stream) {
    const float* s = (const float*)d_in[0];
    const int* nrows = (const int*)d_in[1];
    const int* ncols = (const int*)d_in[2];
    float* out = (float*)d_out;

    const size_t qbytes = (size_t)B_ * N_ * M_ * sizeof(__half);  // 128 MiB
    __half* q = (__half*)d_ws;                                    // ws proven >= 136 MiB
    float* pa = (float*)((char*)d_ws + qbytes);                   // 4 MiB
    float* pb = pa + (size_t)B_ * PCHUNK * M_;                    // 4 MiB

    // Host-side occupancy gate (graph-capture-safe queries; deterministic).
    int dev = 0;
    hipError_t e0 = hipGetDevice(&dev);
    int ncu = 0;
    hipError_t e1 = hipDeviceGetAttribute(&ncu, hipDeviceAttributeMultiprocessorCount, dev);
    int maxbpc = 0;
    hipError_t e2 = hipOccupancyMaxActiveBlocksPerMultiprocessor(&maxbpc, sink_coop, 256, 0);
    const bool qok = (e0 == hipSuccess) && (e1 == hipSuccess) && (e2 == hipSuccess);
    const long cap = qok ? (long)maxbpc * (long)ncu : 0;

    if (cap >= 256) {  // enough co-resident blocks for a sane cooperative run
        const int G = (int)((cap < (long)NVB) ? cap : (long)NVB);
        void* args[] = {(void*)&s, (void*)&q, (void*)&pa, (void*)&pb,
                        (void*)&out, (void*)&nrows, (void*)&ncols};
        hipError_t e3 = hipLaunchCooperativeKernel((void*)sink_coop, dim3(G), dim3(256),
                                                   args, 0, stream);
        if (e3 == hipSuccess) return;
        // fall through to the proven multi-dispatch path on launch failure
    }
    {
        const dim3 blk(256);
        const dim3 g_chunk(PCHUNK, B_);
        prep_pass<<<g_chunk, blk, 0, stream>>>(s, q, pa, nrows, ncols);
        fused_pass_h<<<g_chunk, blk, 0, stream>>>(q, pa, pb, nrows, ncols);
        fused_pass_h<<<g_chunk, blk, 0, stream>>>(q, pb, pa, nrows, ncols);
        fused_pass_h<<<g_chunk, blk, 0, stream>>>(q, pa, pb, nrows, ncols);
        fused_pass_h<<<g_chunk, blk, 0, stream>>>(q, pb, pa, nrows, ncols);
        final_pass_h<<<g_chunk, blk, 0, stream>>>(q, pa, out, nrows, ncols);
    }
}

// Round 10
// 229.366 us; speedup vs baseline: 2.4383x; 2.4383x over previous
//
#include <hip/hip_runtime.h>
#include <hip/hip_fp16.h>

// Masked Sinkhorn via diagonal-scaling algebra on A = s+EPS:
//   c <- 1/(A^T r), r <- 1/(A c), out = A ∘ (r9 c8^T) on valid block.
// R10: ONE kernel, per-BATCH synchronization. The 64 batch elements are
// independent; only the 16 blocks of one batch sync between phases (atomic
// counter barrier, ~us) instead of 6 dispatches (launch gaps + tail idle)
// or grid.sync (R9: ~130us per sync on 8-XCD MI355X -> 887us total).
// Phase bodies identical to R7's proven 230us kernels -> absmax 3.0518e-05.
// Host occupancy gate guarantees all 1024 blocks co-resident; else R7 path.

namespace {
constexpr int B_ = 64;
constexpr int N_ = 1024;
constexpr int M_ = 1024;
constexpr float EPS_ = 1e-4f;
constexpr int PCHUNK = 16;        // row chunks / blocks per batch
constexpr int RPC = N_ / PCHUNK;  // 64 rows per chunk
constexpr int NPHASE_BARRIERS = 8;  // counters per batch (5 used)
}

typedef float f32x4_ __attribute__((ext_vector_type(4)));

__device__ __forceinline__ float4 nt_load4(const float* p) {
    f32x4_ v = __builtin_nontemporal_load(reinterpret_cast<const f32x4_*>(p));
    return float4{v.x, v.y, v.z, v.w};
}

// ---------------------------------------------------------------------------
// Phase bodies (identical math to R7's kernels).
// ---------------------------------------------------------------------------
__device__ __forceinline__ void prep_body(int b, int p,
                                          const float* __restrict__ s,
                                          __half* __restrict__ q,
                                          float* __restrict__ partial,
                                          const int* __restrict__ nrows,
                                          const int* __restrict__ ncols,
                                          float (*lds)[M_]) {
    const int nr = nrows[b], nc = ncols[b];
    const int wave = threadIdx.x >> 6, lane = threadIdx.x & 63;

    float4 ca[4];
#pragma unroll
    for (int t = 0; t < 4; ++t) ca[t] = float4{0.f, 0.f, 0.f, 0.f};

    const int rbeg = p * RPC + wave * 16;
    const int rend = min(rbeg + 16, nr);
    const float* sb = s + (size_t)b * N_ * M_;
    __half* qb = q + (size_t)b * N_ * M_;

    for (int n = rbeg; n < rend; ++n) {
#pragma unroll
        for (int t = 0; t < 4; ++t) {
            const int m0 = t * 256 + lane * 4;
            float4 v = {0.f, 0.f, 0.f, 0.f};
            if (m0 < nc) {
                v = nt_load4(sb + (size_t)n * M_ + m0);
                v.x += EPS_; v.y += EPS_; v.z += EPS_; v.w += EPS_;
            }
            __half2 h01 = __floats2half2_rn(v.x, v.y);
            __half2 h23 = __floats2half2_rn(v.z, v.w);
            uint2 st;
            st.x = *reinterpret_cast<const unsigned*>(&h01);
            st.y = *reinterpret_cast<const unsigned*>(&h23);
            *reinterpret_cast<uint2*>(qb + (size_t)n * M_ + m0) = st;
            ca[t].x += v.x; ca[t].y += v.y; ca[t].z += v.z; ca[t].w += v.w;
        }
    }
    __syncthreads();  // LDS reuse safety
#pragma unroll
    for (int t = 0; t < 4; ++t)
        *reinterpret_cast<float4*>(&lds[wave][t * 256 + lane * 4]) = ca[t];
    __syncthreads();
    const int m0 = threadIdx.x * 4;
    const float4 a0 = *reinterpret_cast<const float4*>(&lds[0][m0]);
    const float4 a1 = *reinterpret_cast<const float4*>(&lds[1][m0]);
    const float4 a2 = *reinterpret_cast<const float4*>(&lds[2][m0]);
    const float4 a3 = *reinterpret_cast<const float4*>(&lds[3][m0]);
    float4 o;
    o.x = a0.x + a1.x + a2.x + a3.x;
    o.y = a0.y + a1.y + a2.y + a3.y;
    o.z = a0.z + a1.z + a2.z + a3.z;
    o.w = a0.w + a1.w + a2.w + a3.w;
    *reinterpret_cast<float4*>(partial + ((size_t)b * PCHUNK + p) * M_ + m0) = o;
}

__device__ __forceinline__ void fused_body(int b, int p,
                                           const __half* __restrict__ q,
                                           const float* __restrict__ partial_in,
                                           float* __restrict__ partial_out,
                                           const int* __restrict__ nrows,
                                           const int* __restrict__ ncols,
                                           float (*lds)[M_]) {
    const int nr = nrows[b], nc = ncols[b];
    const int wave = threadIdx.x >> 6, lane = threadIdx.x & 63;

    __syncthreads();  // LDS reuse safety
    {
        const int m0 = threadIdx.x * 4;
        const float* pp = partial_in + (size_t)b * PCHUNK * M_ + m0;
        float4 sacc = {0.f, 0.f, 0.f, 0.f};
#pragma unroll
        for (int i = 0; i < PCHUNK; ++i) {
            const float4 v = *reinterpret_cast<const float4*>(pp + (size_t)i * M_);
            sacc.x += v.x; sacc.y += v.y; sacc.z += v.z; sacc.w += v.w;
        }
        float4 cv;
        cv.x = (sacc.x == 0.f) ? 1.f : 1.f / sacc.x;
        cv.y = (sacc.y == 0.f) ? 1.f : 1.f / sacc.y;
        cv.z = (sacc.z == 0.f) ? 1.f : 1.f / sacc.z;
        cv.w = (sacc.w == 0.f) ? 1.f : 1.f / sacc.w;
        *reinterpret_cast<float4*>(&lds[0][m0]) = cv;
    }
    __syncthreads();

    float cm[16];
#pragma unroll
    for (int t = 0; t < 2; ++t)
#pragma unroll
        for (int j = 0; j < 8; ++j) {
            const int m = t * 512 + lane * 8 + j;
            const float v = lds[0][m];
            cm[t * 8 + j] = (m < nc) ? v : 0.f;
        }
    __syncthreads();  // lds reused below

    float ca[16];
#pragma unroll
    for (int k = 0; k < 16; ++k) ca[k] = 0.f;

    const int rbeg = p * RPC + wave * 16;
    const int rend = min(rbeg + 16, nr);
    const __half* qb = q + (size_t)b * N_ * M_;

    for (int n = rbeg; n < rend; ++n) {
        float f[16];
#pragma unroll
        for (int t = 0; t < 2; ++t) {
            const float4 raw = *reinterpret_cast<const float4*>(
                qb + (size_t)n * M_ + t * 512 + lane * 8);
            const __half2* hp = reinterpret_cast<const __half2*>(&raw);
#pragma unroll
            for (int k = 0; k < 4; ++k) {
                const float2 fr = __half22float2(hp[k]);
                f[t * 8 + 2 * k] = fr.x;
                f[t * 8 + 2 * k + 1] = fr.y;
            }
        }
        float acc = 0.f;
#pragma unroll
        for (int k = 0; k < 16; ++k) acc = fmaf(f[k], cm[k], acc);
#pragma unroll
        for (int off = 1; off < 64; off <<= 1)
            acc += __shfl_xor(acc, off, 64);
        const float rn = 1.f / acc;
#pragma unroll
        for (int k = 0; k < 16; ++k) ca[k] = fmaf(f[k], rn, ca[k]);
    }

#pragma unroll
    for (int t = 0; t < 2; ++t) {
        float4 v0 = {ca[t * 8 + 0], ca[t * 8 + 1], ca[t * 8 + 2], ca[t * 8 + 3]};
        float4 v1 = {ca[t * 8 + 4], ca[t * 8 + 5], ca[t * 8 + 6], ca[t * 8 + 7]};
        *reinterpret_cast<float4*>(&lds[wave][t * 512 + lane * 8]) = v0;
        *reinterpret_cast<float4*>(&lds[wave][t * 512 + lane * 8 + 4]) = v1;
    }
    __syncthreads();
    const int m0 = threadIdx.x * 4;
    const float4 a0 = *reinterpret_cast<const float4*>(&lds[0][m0]);
    const float4 a1 = *reinterpret_cast<const float4*>(&lds[1][m0]);
    const float4 a2 = *reinterpret_cast<const float4*>(&lds[2][m0]);
    const float4 a3 = *reinterpret_cast<const float4*>(&lds[3][m0]);
    float4 o;
    o.x = a0.x + a1.x + a2.x + a3.x;
    o.y = a0.y + a1.y + a2.y + a3.y;
    o.z = a0.z + a1.z + a2.z + a3.z;
    o.w = a0.w + a1.w + a2.w + a3.w;
    *reinterpret_cast<float4*>(partial_out + ((size_t)b * PCHUNK + p) * M_ + m0) = o;
}

__device__ __forceinline__ void final_body(int b, int p,
                                           const __half* __restrict__ q,
                                           const float* __restrict__ partial_in,
                                           float* __restrict__ out,
                                           const int* __restrict__ nrows,
                                           const int* __restrict__ ncols,
                                           float* ldsc) {
    const int nr = nrows[b], nc = ncols[b];
    const int wave = threadIdx.x >> 6, lane = threadIdx.x & 63;

    __syncthreads();  // LDS reuse safety
    {
        const int m0 = threadIdx.x * 4;
        const float* pp = partial_in + (size_t)b * PCHUNK * M_ + m0;
        float4 sacc = {0.f, 0.f, 0.f, 0.f};
#pragma unroll
        for (int i = 0; i < PCHUNK; ++i) {
            const float4 v = *reinterpret_cast<const float4*>(pp + (size_t)i * M_);
            sacc.x += v.x; sacc.y += v.y; sacc.z += v.z; sacc.w += v.w;
        }
        float4 cv;
        cv.x = (sacc.x == 0.f) ? 1.f : 1.f / sacc.x;
        cv.y = (sacc.y == 0.f) ? 1.f : 1.f / sacc.y;
        cv.z = (sacc.z == 0.f) ? 1.f : 1.f / sacc.z;
        cv.w = (sacc.w == 0.f) ? 1.f : 1.f / sacc.w;
        *reinterpret_cast<float4*>(&ldsc[m0]) = cv;
    }
    __syncthreads();

    float cm[16];
#pragma unroll
    for (int t = 0; t < 2; ++t)
#pragma unroll
        for (int j = 0; j < 8; ++j) {
            const int m = t * 512 + lane * 8 + j;
            const float v = ldsc[m];
            cm[t * 8 + j] = (m < nc) ? v : 0.f;
        }

    const int rbeg = p * RPC + wave * 16;
    const __half* qb = q + (size_t)b * N_ * M_;
    float* ob = out + (size_t)b * N_ * M_;

    for (int n = rbeg; n < rbeg + 16; ++n) {
        if (n >= nr) {
            const float4 z = {0.f, 0.f, 0.f, 0.f};
#pragma unroll
            for (int t = 0; t < 2; ++t) {
                *reinterpret_cast<float4*>(ob + (size_t)n * M_ + t * 512 + lane * 8) = z;
                *reinterpret_cast<float4*>(ob + (size_t)n * M_ + t * 512 + lane * 8 + 4) = z;
            }
            continue;
        }
        float f[16];
#pragma unroll
        for (int t = 0; t < 2; ++t) {
            const float4 raw = *reinterpret_cast<const float4*>(
                qb + (size_t)n * M_ + t * 512 + lane * 8);
            const __half2* hp = reinterpret_cast<const __half2*>(&raw);
#pragma unroll
            for (int k = 0; k < 4; ++k) {
                const float2 fr = __half22float2(hp[k]);
                f[t * 8 + 2 * k] = fr.x;
                f[t * 8 + 2 * k + 1] = fr.y;
            }
        }
        float acc = 0.f;
#pragma unroll
        for (int k = 0; k < 16; ++k) acc = fmaf(f[k], cm[k], acc);
#pragma unroll
        for (int off = 1; off < 64; off <<= 1)
            acc += __shfl_xor(acc, off, 64);
        const float rn = 1.f / acc;
#pragma unroll
        for (int t = 0; t < 2; ++t) {
            float4 o0, o1;
            o0.x = f[t * 8 + 0] * rn * cm[t * 8 + 0];
            o0.y = f[t * 8 + 1] * rn * cm[t * 8 + 1];
            o0.z = f[t * 8 + 2] * rn * cm[t * 8 + 2];
            o0.w = f[t * 8 + 3] * rn * cm[t * 8 + 3];
            o1.x = f[t * 8 + 4] * rn * cm[t * 8 + 4];
            o1.y = f[t * 8 + 5] * rn * cm[t * 8 + 5];
            o1.z = f[t * 8 + 6] * rn * cm[t * 8 + 6];
            o1.w = f[t * 8 + 7] * rn * cm[t * 8 + 7];
            *reinterpret_cast<float4*>(ob + (size_t)n * M_ + t * 512 + lane * 8) = o0;
            *reinterpret_cast<float4*>(ob + (size_t)n * M_ + t * 512 + lane * 8 + 4) = o1;
        }
    }
}

// ---------------------------------------------------------------------------
// Per-batch 16-block barrier: release fence + arrive, spin until 16, acquire.
// Counters zeroed per launch via hipMemsetAsync. Deterministic output: every
// consumer reads partials only after all 16 producers arrived.
__device__ __forceinline__ void batch_barrier(int* ctr) {
    __syncthreads();
    if (threadIdx.x == 0) {
        __threadfence();           // release: publish this block's partials
        atomicAdd(ctr, 1);         // device-scope by default on CDNA
        while (__hip_atomic_load(ctr, __ATOMIC_RELAXED, __HIP_MEMORY_SCOPE_AGENT) < PCHUNK) {
            __builtin_amdgcn_s_sleep(1);
        }
        __threadfence();           // acquire: see other blocks' partials
    }
    __syncthreads();
}

// ---------------------------------------------------------------------------
// Single-dispatch kernel: grid (PCHUNK, B). Each batch's 16 blocks run all 6
// phases, syncing only among themselves -> batches pipeline independently.
__global__ void sink_batch(const float* __restrict__ s, __half* __restrict__ q,
                           float* __restrict__ pa, float* __restrict__ pb,
                           float* __restrict__ out, const int* __restrict__ nrows,
                           const int* __restrict__ ncols, int* __restrict__ ctrs) {
    __shared__ float lds[4][M_];
    const int b = blockIdx.y, p = blockIdx.x;
    int* c = ctrs + b * NPHASE_BARRIERS;

    prep_body(b, p, s, q, pa, nrows, ncols, lds);
    batch_barrier(c + 0);
    fused_body(b, p, q, pa, pb, nrows, ncols, lds);  // c0->r1->p(c2)
    batch_barrier(c + 1);
    fused_body(b, p, q, pb, pa, nrows, ncols, lds);  // c2->r3->p(c4)
    batch_barrier(c + 2);
    fused_body(b, p, q, pa, pb, nrows, ncols, lds);  // c4->r5->p(c6)
    batch_barrier(c + 3);
    fused_body(b, p, q, pb, pa, nrows, ncols, lds);  // c6->r7->p(c8)
    batch_barrier(c + 4);
    final_body(b, p, q, pa, out, nrows, ncols, lds[0]);  // c8->r9->out
}

// ---------------------------------------------------------------------------
// Fallback: R7's proven 6-dispatch path (same bodies).
__global__ void prep_pass(const float* __restrict__ s, __half* __restrict__ q,
                          float* __restrict__ partial,
                          const int* __restrict__ nrows, const int* __restrict__ ncols) {
    __shared__ float lds[4][M_];
    prep_body(blockIdx.y, blockIdx.x, s, q, partial, nrows, ncols, lds);
}
__global__ void fused_pass_h(const __half* __restrict__ q,
                             const float* __restrict__ partial_in,
                             float* __restrict__ partial_out,
                             const int* __restrict__ nrows, const int* __restrict__ ncols) {
    __shared__ float lds[4][M_];
    fused_body(blockIdx.y, blockIdx.x, q, partial_in, partial_out, nrows, ncols, lds);
}
__global__ void final_pass_h(const __half* __restrict__ q,
                             const float* __restrict__ partial_in,
                             float* __restrict__ out,
                             const int* __restrict__ nrows, const int* __restrict__ ncols) {
    __shared__ float ldsc[M_];
    final_body(blockIdx.y, blockIdx.x, q, partial_in, out, nrows, ncols, ldsc);
}

// ---------------------------------------------------------------------------
extern "C" void kernel_launch(void* const* d_in, const int* in_sizes, int n_in,
                              void* d_out, int out_size, void* d_ws, size_t ws_size,
                              hipStream_t stream) {
    const float* s = (const float*)d_in[0];
    const int* nrows = (const int*)d_in[1];
    const int* ncols = (const int*)d_in[2];
    float* out = (float*)d_out;

    const size_t qbytes = (size_t)B_ * N_ * M_ * sizeof(__half);      // 128 MiB
    const size_t pbytes = (size_t)B_ * PCHUNK * M_ * sizeof(float);   // 4 MiB
    const size_t cbytes = (size_t)B_ * NPHASE_BARRIERS * sizeof(int); // 2 KiB
    __half* q = (__half*)d_ws;
    float* pa = (float*)((char*)d_ws + qbytes);
    float* pb = pa + (size_t)B_ * PCHUNK * M_;
    int* ctrs = (int*)((char*)d_ws + qbytes + 2 * pbytes);

    const dim3 blk(256);
    const dim3 g_chunk(PCHUNK, B_);

    // Co-residency gate: the barrier path needs all 1024 blocks resident.
    int dev = 0, ncu = 0, maxbpc = 0;
    hipError_t e0 = hipGetDevice(&dev);
    hipError_t e1 = hipDeviceGetAttribute(&ncu, hipDeviceAttributeMultiprocessorCount, dev);
    hipError_t e2 = hipOccupancyMaxActiveBlocksPerMultiprocessor(&maxbpc, sink_batch, 256, 0);
    const bool qok = (e0 == hipSuccess) && (e1 == hipSuccess) && (e2 == hipSuccess);
    const long cap = qok ? (long)maxbpc * (long)ncu : 0;
    const bool ws_ok = ws_size >= qbytes + 2 * pbytes + cbytes;

    if (ws_ok && cap >= (long)(PCHUNK * B_)) {
        hipError_t em = hipMemsetAsync(ctrs, 0, cbytes, stream);
        if (em == hipSuccess) {
            sink_batch<<<g_chunk, blk, 0, stream>>>(s, q, pa, pb, out, nrows, ncols, ctrs);
            return;
        }
    }
    // Proven R7 6-dispatch path.
    prep_pass<<<g_chunk, blk, 0, stream>>>(s, q, pa, nrows, ncols);
    fused_pass_h<<<g_chunk, blk, 0, stream>>>(q, pa, pb, nrows, ncols);
    fused_pass_h<<<g_chunk, blk, 0, stream>>>(q, pb, pa, nrows, ncols);
    fused_pass_h<<<g_chunk, blk, 0, stream>>>(q, pa, pb, nrows, ncols);
    fused_pass_h<<<g_chunk, blk, 0, stream>>>(q, pb, pa, nrows, ncols);
    final_pass_h<<<g_chunk, blk, 0, stream>>>(q, pa, out, nrows, ncols);
}